// Round 2
// baseline (563.680 us; speedup 1.0000x reference)
//
#include <hip/hip_runtime.h>
#include <math.h>

#define BD 8
#define CD 256
#define ND 4096
#define DA 64
#define HM 2048   // m-half processed per pass (P buffer covers one half)
#define OSTR 260  // O accumulator row stride (256 c + rs @256, padded to x4)

typedef __attribute__((ext_vector_type(8))) short short8v;
typedef __attribute__((ext_vector_type(4))) float float4v;

static __device__ __forceinline__ float4v mfma16(short8v a, short8v b, float4v c) {
  return __builtin_amdgcn_mfma_f32_16x16x32_bf16(a, b, c, 0, 0, 0);
}
static __device__ __forceinline__ unsigned short f2bf(float f) {
  union { float f; unsigned int u; } v; v.f = f;
  return (unsigned short)((v.u + 0x7fffu + ((v.u >> 16) & 1u)) >> 16);
}
static __device__ __forceinline__ float bf2f(unsigned short h) {
  union { unsigned int u; float f; } v; v.u = (unsigned int)h << 16;
  return v.f;
}
// XOR-swizzled LDS offset (ushort units) for rows of 64 bf16 (8 x 16B chunks).
static __device__ __forceinline__ int sw(int row, int c8) {
  return row * 64 + (((c8) ^ (row & 7)) << 3);
}
typedef const __attribute__((address_space(1))) unsigned int g_u32;
typedef __attribute__((address_space(3))) unsigned int l_u32;
static __device__ __forceinline__ void gld16(const void* g, void* l) {
  __builtin_amdgcn_global_load_lds((g_u32*)g, (l_u32*)l, 16, 0, 0);
}

// ---------------------------------------------------------------------------
// k_prep: x [b][c][n] fp32 -> xTh/xTl [b][n][256] split bf16 (transposed).
// ---------------------------------------------------------------------------
__global__ __launch_bounds__(256) void k_prep(const float* __restrict__ x,
                                              unsigned short* __restrict__ xTh,
                                              unsigned short* __restrict__ xTl) {
  const int n0 = blockIdx.x * 64, c0 = blockIdx.y * 64, b = blockIdx.z;
  __shared__ float Xs[64][68];
  const int tid = threadIdx.x;
  const int r0 = tid >> 4, col4 = (tid & 15) * 4;
#pragma unroll
  for (int j = 0; j < 4; ++j) {
    int r = r0 + j * 16;
    *(float4*)&Xs[r][col4] =
        *(const float4*)&x[((size_t)(b * CD + c0 + r)) * ND + n0 + col4];
  }
  __syncthreads();
  const int n = tid >> 2, cg = (tid & 3) * 16;
  unsigned short h[16], l[16];
#pragma unroll
  for (int j = 0; j < 16; ++j) {
    float v = Xs[cg + j][n];
    h[j] = f2bf(v);
    l[j] = f2bf(v - bf2f(h[j]));
  }
  size_t o = ((size_t)b * ND + n0 + n) * CD + c0 + cg;
#pragma unroll
  for (int j = 0; j < 4; ++j) {
    *(ushort4*)&xTh[o + j * 4] = *(ushort4*)&h[j * 4];
    *(ushort4*)&xTl[o + j * 4] = *(ushort4*)&l[j * 4];
  }
}

// ---------------------------------------------------------------------------
// k_prepW: split weights fp32 -> bf16 hi/lo. Wch/Wcl = [Wq;Wk;Wv] rows 0..383.
// ---------------------------------------------------------------------------
__global__ void k_prepW(const float* __restrict__ Wq, const float* __restrict__ Wk,
                        const float* __restrict__ Wv, const float* __restrict__ Wp,
                        unsigned short* Wch, unsigned short* Wcl,
                        unsigned short* Wph, unsigned short* Wpl) {
  int i = blockIdx.x * 256 + threadIdx.x;  // 640 rows x 64 float4
  int row = i >> 6, c4 = (i & 63) * 4;
  const float* src; unsigned short *dh, *dl; int r, drow;
  if (row < 64)       { src = Wq; r = row;       dh = Wch; dl = Wcl; drow = row; }
  else if (row < 128) { src = Wk; r = row - 64;  dh = Wch; dl = Wcl; drow = row; }
  else if (row < 384) { src = Wv; r = row - 128; dh = Wch; dl = Wcl; drow = row; }
  else                { src = Wp; r = row - 384; dh = Wph; dl = Wpl; drow = row - 384; }
  float4 f = *(const float4*)&src[(size_t)r * 256 + c4];
  ushort4 hh, ll;
  hh.x = f2bf(f.x); hh.y = f2bf(f.y); hh.z = f2bf(f.z); hh.w = f2bf(f.w);
  ll.x = f2bf(f.x - bf2f(hh.x)); ll.y = f2bf(f.y - bf2f(hh.y));
  ll.z = f2bf(f.z - bf2f(hh.z)); ll.w = f2bf(f.w - bf2f(hh.w));
  *(ushort4*)&dh[(size_t)drow * 256 + c4] = hh;
  *(ushort4*)&dl[(size_t)drow * 256 + c4] = ll;
}

// ---------------------------------------------------------------------------
// k_proj: MERGED q/k/v projection (reads xT once, LDS k-slices, 3-product).
// grid (ND/128, B), 512 thr. q: hi only; k: hi+lo; v: transposed bf16.
// ---------------------------------------------------------------------------
__global__ __launch_bounds__(512) void k_proj(
    const unsigned short* __restrict__ xTh, const unsigned short* __restrict__ xTl,
    const unsigned short* __restrict__ Wch, const unsigned short* __restrict__ Wcl,
    unsigned short* __restrict__ qh, unsigned short* __restrict__ kh,
    unsigned short* __restrict__ kl, unsigned short* __restrict__ vT) {
  const int n0 = blockIdx.x * 128, b = blockIdx.y;
  const int tid = threadIdx.x, w = tid >> 6, lane = tid & 63, lq = lane & 15,
            quad = lane >> 4;
  __shared__ __align__(16) unsigned short xs[2][2][128][40];
  float4v O[24];
#pragma unroll
  for (int t = 0; t < 24; ++t) O[t] = (float4v){0.f, 0.f, 0.f, 0.f};

  const int srow = tid >> 2, sc4 = tid & 3;
  uint4 rh, rl;
  auto load_slice = [&](int ks) {
    size_t a = ((size_t)b * ND + n0 + srow) * CD + ks * 32 + sc4 * 8;
    rh = *(const uint4*)(xTh + a);
    rl = *(const uint4*)(xTl + a);
  };
  auto write_slice = [&](int buf) {
    *(uint4*)&xs[buf][0][srow][sc4 * 8] = rh;
    *(uint4*)&xs[buf][1][srow][sc4 * 8] = rl;
  };
  load_slice(0); write_slice(0);
#pragma unroll 1
  for (int ks = 0; ks < 8; ++ks) {
    __syncthreads();
    if (ks < 7) load_slice(ks + 1);
    short8v bxh = *(const short8v*)&xs[ks & 1][0][w * 16 + lq][quad * 8];
    short8v bxl = *(const short8v*)&xs[ks & 1][1][w * 16 + lq][quad * 8];
#pragma unroll
    for (int t = 0; t < 24; ++t) {
      size_t a = (size_t)(t * 16 + lq) * CD + ks * 32 + quad * 8;
      short8v awh = *(const short8v*)(Wch + a);
      short8v awl = *(const short8v*)(Wcl + a);
      O[t] = mfma16(awh, bxh, O[t]);
      O[t] = mfma16(awl, bxh, O[t]);
      O[t] = mfma16(awh, bxl, O[t]);
    }
    if (ks < 7) write_slice((ks + 1) & 1);
  }
  const int n = n0 + w * 16 + lq;
#pragma unroll
  for (int t = 0; t < 24; ++t) {
    if (t < 4) {
      ushort4 hh;
      hh.x = f2bf(O[t][0]); hh.y = f2bf(O[t][1]);
      hh.z = f2bf(O[t][2]); hh.w = f2bf(O[t][3]);
      *(ushort4*)&qh[((size_t)b * ND + n) * DA + t * 16 + quad * 4] = hh;
    } else if (t < 8) {
      ushort4 hh, ll;
      hh.x = f2bf(O[t][0]); hh.y = f2bf(O[t][1]);
      hh.z = f2bf(O[t][2]); hh.w = f2bf(O[t][3]);
      ll.x = f2bf(O[t][0] - bf2f(hh.x)); ll.y = f2bf(O[t][1] - bf2f(hh.y));
      ll.z = f2bf(O[t][2] - bf2f(hh.z)); ll.w = f2bf(O[t][3] - bf2f(hh.w));
      size_t o = ((size_t)b * ND + n) * DA + (t - 4) * 16 + quad * 4;
      *(ushort4*)&kh[o] = hh;
      *(ushort4*)&kl[o] = ll;
    } else {
#pragma unroll
      for (int r = 0; r < 4; ++r) {
        int c = (t - 8) * 16 + quad * 4 + r;
        vT[((size_t)b * CD + c) * ND + n] = f2bf(O[t][r]);
      }
    }
  }
}

// ---------------------------------------------------------------------------
// k_expE: E = q.k^T (2-product split bf16, SWAPPED operands so each lane holds
// 4 consecutive m), P = trunc_bf16(exp(E)) streamed to HBM via LDS-staged
// coalesced 256B stores, plus per-m column sums (Dp partials).
// One m-half per launch: P[b][n][HM]. grid (16 mtiles, 4 nquarters, 8 b).
// ---------------------------------------------------------------------------
__global__ __launch_bounds__(512, 4) void k_expE(
    const unsigned short* __restrict__ qh, const unsigned short* __restrict__ khp,
    const unsigned short* __restrict__ klp, unsigned short* __restrict__ P,
    float* __restrict__ Dp, int mhalf) {
  const int mtile = blockIdx.x, nq4 = blockIdx.y, b = blockIdx.z;
  const int m0 = mhalf * HM + mtile * 128;  // global m base
  const int mmb = mtile * 128;              // m base within P half
  const int nbase = nq4 * 1024;
  const int tid = threadIdx.x, w = tid >> 6, lane = tid & 63, lq = lane & 15,
            quad = lane >> 4;
  const int mq = w & 3, nh = w >> 2;
  __shared__ __align__(16) unsigned short qbuf[2][4096];  // 64n x 64d swizzled
  __shared__ __align__(16) unsigned short Et[64][136];    // staged E-tile (pad->no conflict)
  __shared__ float Cb[128];
  // K frags resident (rows = m), used as A-operand (swapped mfma)
  short8v bkh[2][2], bkl[2][2];
#pragma unroll
  for (int sub = 0; sub < 2; ++sub)
#pragma unroll
    for (int k = 0; k < 2; ++k) {
      size_t a = ((size_t)b * ND + m0 + mq * 32 + sub * 16 + lq) * DA + k * 32 + quad * 8;
      bkh[sub][k] = *(const short8v*)(khp + a);
      bkl[sub][k] = *(const short8v*)(klp + a);
    }
  const int srow = tid >> 3, sck = tid & 7;
  auto stageQ = [&](int it, int buf) {
    const unsigned short* src = qh + ((size_t)b * ND + nbase + it * 64 + srow) * DA +
                                ((sck ^ (srow & 7)) << 3);
    gld16(src, &qbuf[buf][0] + (size_t)w * 512);
  };
  float cs[2][4] = {{0.f, 0.f, 0.f, 0.f}, {0.f, 0.f, 0.f, 0.f}};
  stageQ(0, 0);
  asm volatile("s_waitcnt vmcnt(0)\n\ts_barrier" ::: "memory");
#pragma unroll 1
  for (int i = 0; i < 16; ++i) {
    if (i < 15) stageQ(i + 1, (i + 1) & 1);
#pragma unroll
    for (int s = 0; s < 2; ++s) {
      short8v ah[2];
#pragma unroll
      for (int k = 0; k < 2; ++k)
        ah[k] = *(const short8v*)&qbuf[i & 1][sw(nh * 32 + s * 16 + lq, k * 4 + quad)];
#pragma unroll
      for (int sub = 0; sub < 2; ++sub) {
        float4v acc = {0.f, 0.f, 0.f, 0.f};
#pragma unroll
        for (int k = 0; k < 2; ++k) {
          acc = mfma16(bkh[sub][k], ah[k], acc);
          acc = mfma16(bkl[sub][k], ah[k], acc);
        }
        // lane holds E[m = m0+mq*32+sub*16+quad*4+r][n = nbase+i*64+nh*32+s*16+lq]
        float p0 = __expf(acc[0]), p1 = __expf(acc[1]);
        float p2 = __expf(acc[2]), p3 = __expf(acc[3]);
        cs[sub][0] += p0; cs[sub][1] += p1; cs[sub][2] += p2; cs[sub][3] += p3;
        unsigned int w0 =
            (__float_as_uint(p0) >> 16) | (__float_as_uint(p1) & 0xffff0000u);
        unsigned int w1 =
            (__float_as_uint(p2) >> 16) | (__float_as_uint(p3) & 0xffff0000u);
        const int nl = nh * 32 + s * 16 + lq;
        uint2 wv; wv.x = w0; wv.y = w1;
        *(uint2*)((unsigned short*)Et + nl * 136 + mq * 32 + sub * 16 + quad * 4) = wv;
      }
    }
    // Et visible (LDS only; gld16(i+1) stays in flight across this barrier)
    asm volatile("s_waitcnt lgkmcnt(0)\n\ts_barrier" ::: "memory");
    {  // coalesced readback: 256B segments per 8 threads
      uint4 u0 = *(const uint4*)((const unsigned short*)Et + srow * 136 + sck * 16);
      uint4 u1 = *(const uint4*)((const unsigned short*)Et + srow * 136 + sck * 16 + 8);
      size_t po = ((size_t)b * ND + nbase + i * 64 + srow) * HM + mmb + sck * 16;
      *(uint4*)(P + po) = u0;
      *(uint4*)(P + po + 8) = u1;
    }
    // retire gld16(i+1) (oldest), keep the 2 P-stores in flight
    asm volatile("s_waitcnt vmcnt(2) lgkmcnt(0)\n\ts_barrier" ::: "memory");
  }
  // ---- column sums: reduce over lq (16 n), combine nh halves in LDS ----
#pragma unroll
  for (int sub = 0; sub < 2; ++sub)
#pragma unroll
    for (int r = 0; r < 4; ++r) {
      cs[sub][r] += __shfl_xor(cs[sub][r], 1);
      cs[sub][r] += __shfl_xor(cs[sub][r], 2);
      cs[sub][r] += __shfl_xor(cs[sub][r], 4);
      cs[sub][r] += __shfl_xor(cs[sub][r], 8);
    }
  if (nh == 0 && lq == 0) {
#pragma unroll
    for (int sub = 0; sub < 2; ++sub) {
      float4 v4; v4.x = cs[sub][0]; v4.y = cs[sub][1]; v4.z = cs[sub][2]; v4.w = cs[sub][3];
      *(float4*)&Cb[mq * 32 + sub * 16 + quad * 4] = v4;
    }
  }
  __syncthreads();
  if (nh == 1 && lq == 0) {
#pragma unroll
    for (int sub = 0; sub < 2; ++sub) {
      float4 v4 = *(const float4*)&Cb[mq * 32 + sub * 16 + quad * 4];
      v4.x += cs[sub][0]; v4.y += cs[sub][1]; v4.z += cs[sub][2]; v4.w += cs[sub][3];
      *(float4*)&Dp[((size_t)nq4 * 8 + b) * HM + mmb + mq * 32 + sub * 16 + quad * 4] = v4;
    }
  }
}

// drc[b][mhalf*HM + mm] = 1/sum_q Dp[q][b][mm]. grid 16 x 256.
__global__ void k_rcp2(const float* __restrict__ Dp, float* __restrict__ drc,
                       int mhalf) {
  int i = blockIdx.x * 256 + threadIdx.x;  // 4096 threads, float4 each
  int b = i >> 9, mm = (i & 511) * 4;
  float4 s0 = *(const float4*)&Dp[((size_t)0 * 8 + b) * HM + mm];
  float4 s1 = *(const float4*)&Dp[((size_t)1 * 8 + b) * HM + mm];
  float4 s2 = *(const float4*)&Dp[((size_t)2 * 8 + b) * HM + mm];
  float4 s3 = *(const float4*)&Dp[((size_t)3 * 8 + b) * HM + mm];
  float4 r;
  r.x = 1.f / (s0.x + s1.x + s2.x + s3.x);
  r.y = 1.f / (s0.y + s1.y + s2.y + s3.y);
  r.z = 1.f / (s0.z + s1.z + s2.z + s3.z);
  r.w = 1.f / (s0.w + s1.w + s2.w + s3.w);
  *(float4*)&drc[(size_t)b * ND + mhalf * HM + mm] = r;
}

// vext: scale vT columns of this m-half in place by drc. grid 2048 x 256.
__global__ void k_vext(unsigned short* __restrict__ vT,
                       const float* __restrict__ drc, int mhalf) {
  int idx = blockIdx.x * 256 + threadIdx.x;  // 524288: 8 m per thread
  int m8 = idx & 255, c = (idx >> 8) & 255, b = idx >> 16;
  const int mb = mhalf * HM + m8 * 8;
  size_t va = ((size_t)(b * CD + c)) * ND + mb;
  short8v v = *(const short8v*)(vT + va);
  float4 d0 = *(const float4*)&drc[(size_t)b * ND + mb];
  float4 d1 = *(const float4*)&drc[(size_t)b * ND + mb + 4];
  ushort4 o0, o1;
  o0.x = f2bf(bf2f((unsigned short)v[0]) * d0.x);
  o0.y = f2bf(bf2f((unsigned short)v[1]) * d0.y);
  o0.z = f2bf(bf2f((unsigned short)v[2]) * d0.z);
  o0.w = f2bf(bf2f((unsigned short)v[3]) * d0.w);
  o1.x = f2bf(bf2f((unsigned short)v[4]) * d1.x);
  o1.y = f2bf(bf2f((unsigned short)v[5]) * d1.y);
  o1.z = f2bf(bf2f((unsigned short)v[6]) * d1.z);
  o1.w = f2bf(bf2f((unsigned short)v[7]) * d1.w);
  *(ushort4*)(vT + va) = o0;
  *(ushort4*)(vT + va + 4) = o1;
}

// ---------------------------------------------------------------------------
// k_pv: dense GEMM O[c][n] += vext[c][m] . P[n][m] over this m-half, plus
// rs[n] += P[n][m].drc[m] (VALU ride-along, one owned n-frag per wave).
// A (vext) direct-from-global (L2-hot, 1-ahead reg prefetch); B (P) staged in
// tri-buffered LDS via gld16, counted-vmcnt barriers (stage crosses 2 barriers).
// last=1: add Oa partial, finish y = x - O/rs in place over xhy.
// grid (32 ntiles, 8 b), 512 thr, 8 waves = 4c x 2n.
// ---------------------------------------------------------------------------
__global__ __launch_bounds__(512, 2) void k_pv(
    const unsigned short* __restrict__ P, const unsigned short* __restrict__ vext,
    const float* __restrict__ drc, float* __restrict__ Oa,
    unsigned short* __restrict__ xhy, const unsigned short* __restrict__ xTl,
    int mhalf, int last) {
  const int n0 = blockIdx.x * 128, b = blockIdx.y;
  const int tid = threadIdx.x, w = tid >> 6, lane = tid & 63, lq = lane & 15,
            quad = lane >> 4;
  const int wc = w & 3, wn = w >> 2;
  __shared__ __align__(16) unsigned short pbuf[3][8192];  // [128n][64m] swizzled
  __shared__ float Sb[128];
  float4v O[4][4];  // [tc][tn]
#pragma unroll
  for (int tc = 0; tc < 4; ++tc)
#pragma unroll
    for (int tn = 0; tn < 4; ++tn) O[tc][tn] = (float4v){0.f, 0.f, 0.f, 0.f};
  float rs = 0.f;

  short8v ac[8], an[8];  // A frags [tc*2+s32]
  auto aload = [&](short8v* d, int mm) {
#pragma unroll
    for (int tc = 0; tc < 4; ++tc)
#pragma unroll
      for (int s32 = 0; s32 < 2; ++s32)
        d[tc * 2 + s32] = *(const short8v*)(
            vext + ((size_t)(b * CD) + wc * 64 + tc * 16 + lq) * ND + mhalf * HM +
            mm + s32 * 32 + quad * 8);
  };
  float4 dc[4], dn[4];  // drc [s32*2 + half]
  auto dload = [&](float4* d, int mm) {
#pragma unroll
    for (int s32 = 0; s32 < 2; ++s32) {
      size_t a = (size_t)b * ND + mhalf * HM + mm + s32 * 32 + quad * 8;
      d[s32 * 2] = *(const float4*)(drc + a);
      d[s32 * 2 + 1] = *(const float4*)(drc + a + 4);
    }
  };
  auto stageP = [&](int mt, int vn) {  // P-tile [128n][64m], pre-swizzled src
    unsigned short* base = &pbuf[vn][0];
#pragma unroll
    for (int j = 0; j < 2; ++j) {
      int cidx = tid + j * 512;
      int row = cidx >> 3, ck = cidx & 7;
      const unsigned short* src = P + ((size_t)b * ND + n0 + row) * HM + mt * 64 +
                                  ((ck ^ (row & 7)) << 3);
      gld16(src, base + (size_t)(w * 64 + j * 512) * 8);
    }
  };

  aload(ac, 0);
  dload(dc, 0);
  stageP(0, 0);
  stageP(1, 1);
  asm volatile("s_waitcnt vmcnt(2)\n\ts_barrier" ::: "memory");

  int rc = 0, vs = 2;
#pragma unroll 1
  for (int i = 0; i < 32; ++i) {
    if (i < 31) {
      aload(an, (i + 1) * 64);
      dload(dn, (i + 1) * 64);
    }
    if (i < 30) {
      stageP(i + 2, vs);
      vs = (vs + 1 == 3) ? 0 : vs + 1;
    }
#pragma unroll
    for (int s32 = 0; s32 < 2; ++s32) {
      short8v bp[4];
#pragma unroll
      for (int tn = 0; tn < 4; ++tn) {
        bp[tn] = *(const short8v*)&pbuf[rc][sw(wn * 64 + tn * 16 + lq, s32 * 4 + quad)];
        if (tn == wc) {  // wave-uniform branch: rs ride-along on owned n-frag
          float4 da = dc[s32 * 2], db = dc[s32 * 2 + 1];
          rs += bf2f((unsigned short)bp[tn][0]) * da.x;
          rs += bf2f((unsigned short)bp[tn][1]) * da.y;
          rs += bf2f((unsigned short)bp[tn][2]) * da.z;
          rs += bf2f((unsigned short)bp[tn][3]) * da.w;
          rs += bf2f((unsigned short)bp[tn][4]) * db.x;
          rs += bf2f((unsigned short)bp[tn][5]) * db.y;
          rs += bf2f((unsigned short)bp[tn][6]) * db.z;
          rs += bf2f((unsigned short)bp[tn][7]) * db.w;
        }
      }
#pragma unroll
      for (int tc = 0; tc < 4; ++tc)
#pragma unroll
        for (int tn = 0; tn < 4; ++tn)
          O[tc][tn] = mfma16(ac[tc * 2 + s32], bp[tn], O[tc][tn]);
    }
    if (i < 31) {
#pragma unroll
      for (int t = 0; t < 8; ++t) ac[t] = an[t];
#pragma unroll
      for (int t = 0; t < 4; ++t) dc[t] = dn[t];
    }
    rc = (rc + 1 == 3) ? 0 : rc + 1;
    if (i < 30)
      asm volatile("s_waitcnt vmcnt(2) lgkmcnt(0)\n\ts_barrier" ::: "memory");
    else if (i == 30)
      asm volatile("s_waitcnt vmcnt(12) lgkmcnt(0)\n\ts_barrier" ::: "memory");
  }

  // rs: reduce over quad (m-slices)
  rs += __shfl_xor(rs, 16);
  rs += __shfl_xor(rs, 32);
  if (!last) {
#pragma unroll
    for (int tc = 0; tc < 4; ++tc)
#pragma unroll
      for (int tn = 0; tn < 4; ++tn) {
        const int n = n0 + wn * 64 + tn * 16 + lq, c = wc * 64 + tc * 16 + quad * 4;
        float4 v4;
        v4.x = O[tc][tn][0]; v4.y = O[tc][tn][1];
        v4.z = O[tc][tn][2]; v4.w = O[tc][tn][3];
        *(float4*)&Oa[((size_t)b * ND + n) * OSTR + c] = v4;
      }
    if (quad == 0)
      Oa[((size_t)b * ND + n0 + wn * 64 + wc * 16 + lq) * OSTR + 256] = rs;
  } else {
    if (quad == 0)
      Sb[wn * 64 + wc * 16 + lq] =
          rs + Oa[((size_t)b * ND + n0 + wn * 64 + wc * 16 + lq) * OSTR + 256];
    __syncthreads();
    float rsc[4];
#pragma unroll
    for (int tn = 0; tn < 4; ++tn)
      rsc[tn] = 1.0f / (1e-9f + Sb[wn * 64 + tn * 16 + lq]);
#pragma unroll
    for (int tc = 0; tc < 4; ++tc)
#pragma unroll
      for (int tn = 0; tn < 4; ++tn) {
        const int n = n0 + wn * 64 + tn * 16 + lq, c = wc * 64 + tc * 16 + quad * 4;
        float4 po = *(const float4*)&Oa[((size_t)b * ND + n) * OSTR + c];
        const size_t off = ((size_t)b * ND + n) * CD + c;
        ushort4 h4 = *(const ushort4*)&xhy[off];
        ushort4 l4 = *(const ushort4*)&xTl[off];
        ushort4 o4;
        o4.x = f2bf(bf2f(h4.x) + bf2f(l4.x) - (O[tc][tn][0] + po.x) * rsc[tn]);
        o4.y = f2bf(bf2f(h4.y) + bf2f(l4.y) - (O[tc][tn][1] + po.y) * rsc[tn]);
        o4.z = f2bf(bf2f(h4.z) + bf2f(l4.z) - (O[tc][tn][2] + po.z) * rsc[tn]);
        o4.w = f2bf(bf2f(h4.w) + bf2f(l4.w) - (O[tc][tn][3] + po.w) * rsc[tn]);
        *(ushort4*)&xhy[off] = o4;
      }
  }
}

// ---------------------------------------------------------------------------
// k_final: h = Wp . y (bf16 MFMA); out = relu(BN(h)) + x.
// ---------------------------------------------------------------------------
__global__ __launch_bounds__(256) void k_final(const unsigned short* __restrict__ y,
                                               const unsigned short* __restrict__ Wpb,
                                               const float* __restrict__ x,
                                               const float* __restrict__ gamma,
                                               const float* __restrict__ beta,
                                               const float* __restrict__ mean,
                                               const float* __restrict__ var,
                                               float* __restrict__ out) {
  const int bid = blockIdx.x;
  const int b = bid & 7;
  const int rem = bid >> 3;
  const int n0 = (rem & 63) * 64;
  const int d0 = (rem >> 6) * 64;
  const int tid = threadIdx.x;
  const int wave = tid >> 6, lane = tid & 63, lq = lane & 15, quad = lane >> 4;
  const int dw = d0 + wave * 16;
  float4v O[4];
#pragma unroll
  for (int s = 0; s < 4; ++s) O[s] = (float4v){0.f, 0.f, 0.f, 0.f};
#pragma unroll
  for (int chh = 0; chh < 8; ++chh) {
    const size_t ab = (size_t)(dw + lq) * CD + chh * 32 + quad * 8;
    short8v a0 = *(const short8v*)(Wpb + ab);
#pragma unroll
    for (int s = 0; s < 4; ++s) {
      const size_t bb = ((size_t)b * ND + n0 + s * 16 + lq) * CD + chh * 32 + quad * 8;
      short8v bv = *(const short8v*)(y + bb);
      O[s] = mfma16(a0, bv, O[s]);
    }
  }
#pragma unroll
  for (int r = 0; r < 4; ++r) {
    const int d = dw + quad * 4 + r;
    const float inv  = gamma[d] / sqrtf(var[d] + 1e-5f);
    const float bias = beta[d] - mean[d] * inv;
#pragma unroll
    for (int s = 0; s < 4; ++s) {
      const int n = n0 + s * 16 + lq;
      const size_t oi = ((size_t)b * CD + d) * ND + n;
      out[oi] = fmaxf(O[s][r] * inv + bias, 0.f) + x[oi];
    }
  }
}

extern "C" void kernel_launch(void* const* d_in, const int* in_sizes, int n_in,
                              void* d_out, int out_size, void* d_ws, size_t ws_size,
                              hipStream_t stream) {
  const float* x     = (const float*)d_in[0];
  const float* Wq    = (const float*)d_in[1];
  const float* Wk    = (const float*)d_in[2];
  const float* Wv    = (const float*)d_in[3];
  const float* Wp    = (const float*)d_in[4];
  const float* gamma = (const float*)d_in[5];
  const float* beta  = (const float*)d_in[6];
  const float* mean  = (const float*)d_in[7];
  const float* var   = (const float*)d_in[8];
  float* out = (float*)d_out;

  char* wsp = (char*)d_ws;
  unsigned short* qhp = (unsigned short*)wsp; wsp += (size_t)BD * ND * DA * 2;
  unsigned short* khp = (unsigned short*)wsp; wsp += (size_t)BD * ND * DA * 2;
  unsigned short* klp = (unsigned short*)wsp; wsp += (size_t)BD * ND * DA * 2;
  unsigned short* vT  = (unsigned short*)wsp; wsp += (size_t)BD * CD * ND * 2;  // -> vext (in place)
  unsigned short* xTh = (unsigned short*)wsp; wsp += (size_t)BD * ND * CD * 2;  // aliased as y
  unsigned short* xTl = (unsigned short*)wsp; wsp += (size_t)BD * ND * CD * 2;
  unsigned short* Wch = (unsigned short*)wsp; wsp += (size_t)384 * 256 * 2;
  unsigned short* Wcl = (unsigned short*)wsp; wsp += (size_t)384 * 256 * 2;
  unsigned short* Wph = (unsigned short*)wsp; wsp += (size_t)256 * 256 * 2;
  unsigned short* Wpl = (unsigned short*)wsp; wsp += (size_t)256 * 256 * 2;
  float* drc = (float*)wsp; wsp += (size_t)BD * ND * 4;          // 128 KB
  float* Dp  = (float*)wsp; wsp += (size_t)4 * BD * HM * 4;      // 256 KB
  float* Oa  = (float*)wsp; wsp += (size_t)BD * ND * OSTR * 4;   // 34.1 MB
  unsigned short* P = (unsigned short*)wsp; wsp += (size_t)BD * ND * HM * 2;  // 134.2 MB
  unsigned short* y = xTh;  // xTh consumed+overwritten by k_pv(last) epilogue

  dim3 blk(256), blk5(512);
  k_prep<<<dim3(ND / 64, CD / 64, BD), blk, 0, stream>>>(x, xTh, xTl);
  k_prepW<<<dim3(160), blk, 0, stream>>>(Wq, Wk, Wv, Wp, Wch, Wcl, Wph, Wpl);
  k_proj<<<dim3(ND / 128, BD), blk5, 0, stream>>>(xTh, xTl, Wch, Wcl, qhp, khp,
                                                  klp, vT);
  for (int h = 0; h < 2; ++h) {
    k_expE<<<dim3(16, 4, BD), blk5, 0, stream>>>(qhp, khp, klp, P, Dp, h);
    k_rcp2<<<dim3(16), blk, 0, stream>>>(Dp, drc, h);
    k_vext<<<dim3(2048), blk, 0, stream>>>(vT, drc, h);
    k_pv<<<dim3(32, BD), blk5, 0, stream>>>(P, vT, drc, Oa, y, xTl, h, h);
  }
  k_final<<<dim3(2048), blk, 0, stream>>>(y, Wph, x, gamma, beta, mean, var, out);
}

// Round 3
// 492.277 us; speedup vs baseline: 1.1450x; 1.1450x over previous
//
#include <hip/hip_runtime.h>
#include <math.h>

#define BD 8
#define CD 256
#define ND 4096
#define DA 64

typedef __attribute__((ext_vector_type(8))) short short8v;
typedef __attribute__((ext_vector_type(4))) float float4v;

static __device__ __forceinline__ float4v mfma16(short8v a, short8v b, float4v c) {
  return __builtin_amdgcn_mfma_f32_16x16x32_bf16(a, b, c, 0, 0, 0);
}
static __device__ __forceinline__ unsigned short f2bf(float f) {
  union { float f; unsigned int u; } v; v.f = f;
  return (unsigned short)((v.u + 0x7fffu + ((v.u >> 16) & 1u)) >> 16);
}
static __device__ __forceinline__ float bf2f(unsigned short h) {
  union { unsigned int u; float f; } v; v.u = (unsigned int)h << 16;
  return v.f;
}
// XOR-swizzled LDS offset (ushort units) for rows of 64 bf16 (8 x 16B chunks).
static __device__ __forceinline__ int sw(int row, int c8) {
  return row * 64 + (((c8) ^ (row & 7)) << 3);
}
typedef const __attribute__((address_space(1))) unsigned int g_u32;
typedef __attribute__((address_space(3))) unsigned int l_u32;
static __device__ __forceinline__ void gld16(const void* g, void* l) {
  __builtin_amdgcn_global_load_lds((g_u32*)g, (l_u32*)l, 16, 0, 0);
}

// ---------------------------------------------------------------------------
// k_prep: x [b][c][n] fp32 -> xTh/xTl [b][n][256] split bf16 (transposed).
// ---------------------------------------------------------------------------
__global__ __launch_bounds__(256) void k_prep(const float* __restrict__ x,
                                              unsigned short* __restrict__ xTh,
                                              unsigned short* __restrict__ xTl) {
  const int n0 = blockIdx.x * 64, c0 = blockIdx.y * 64, b = blockIdx.z;
  __shared__ float Xs[64][68];
  const int tid = threadIdx.x;
  const int r0 = tid >> 4, col4 = (tid & 15) * 4;
#pragma unroll
  for (int j = 0; j < 4; ++j) {
    int r = r0 + j * 16;
    *(float4*)&Xs[r][col4] =
        *(const float4*)&x[((size_t)(b * CD + c0 + r)) * ND + n0 + col4];
  }
  __syncthreads();
  const int n = tid >> 2, cg = (tid & 3) * 16;
  unsigned short h[16], l[16];
#pragma unroll
  for (int j = 0; j < 16; ++j) {
    float v = Xs[cg + j][n];
    h[j] = f2bf(v);
    l[j] = f2bf(v - bf2f(h[j]));
  }
  size_t o = ((size_t)b * ND + n0 + n) * CD + c0 + cg;
#pragma unroll
  for (int j = 0; j < 4; ++j) {
    *(ushort4*)&xTh[o + j * 4] = *(ushort4*)&h[j * 4];
    *(ushort4*)&xTl[o + j * 4] = *(ushort4*)&l[j * 4];
  }
}

// ---------------------------------------------------------------------------
// k_prepW: split weights fp32 -> bf16 hi/lo. Wch/Wcl = [Wq;Wk;Wv] rows 0..383.
// ---------------------------------------------------------------------------
__global__ void k_prepW(const float* __restrict__ Wq, const float* __restrict__ Wk,
                        const float* __restrict__ Wv, const float* __restrict__ Wp,
                        unsigned short* Wch, unsigned short* Wcl,
                        unsigned short* Wph, unsigned short* Wpl) {
  int i = blockIdx.x * 256 + threadIdx.x;  // 640 rows x 64 float4
  int row = i >> 6, c4 = (i & 63) * 4;
  const float* src; unsigned short *dh, *dl; int r, drow;
  if (row < 64)       { src = Wq; r = row;       dh = Wch; dl = Wcl; drow = row; }
  else if (row < 128) { src = Wk; r = row - 64;  dh = Wch; dl = Wcl; drow = row; }
  else if (row < 384) { src = Wv; r = row - 128; dh = Wch; dl = Wcl; drow = row; }
  else                { src = Wp; r = row - 384; dh = Wph; dl = Wpl; drow = row - 384; }
  float4 f = *(const float4*)&src[(size_t)r * 256 + c4];
  ushort4 hh, ll;
  hh.x = f2bf(f.x); hh.y = f2bf(f.y); hh.z = f2bf(f.z); hh.w = f2bf(f.w);
  ll.x = f2bf(f.x - bf2f(hh.x)); ll.y = f2bf(f.y - bf2f(hh.y));
  ll.z = f2bf(f.z - bf2f(hh.z)); ll.w = f2bf(f.w - bf2f(hh.w));
  *(ushort4*)&dh[(size_t)drow * 256 + c4] = hh;
  *(ushort4*)&dl[(size_t)drow * 256 + c4] = ll;
}

// ---------------------------------------------------------------------------
// k_proj: MERGED q/k/v projection (reads xT once, LDS k-slices, 3-product).
// grid (ND/128, B), 512 thr. q: hi only; k: hi+lo; v: transposed bf16.
// ---------------------------------------------------------------------------
__global__ __launch_bounds__(512) void k_proj(
    const unsigned short* __restrict__ xTh, const unsigned short* __restrict__ xTl,
    const unsigned short* __restrict__ Wch, const unsigned short* __restrict__ Wcl,
    unsigned short* __restrict__ qh, unsigned short* __restrict__ kh,
    unsigned short* __restrict__ kl, unsigned short* __restrict__ vT) {
  const int n0 = blockIdx.x * 128, b = blockIdx.y;
  const int tid = threadIdx.x, w = tid >> 6, lane = tid & 63, lq = lane & 15,
            quad = lane >> 4;
  __shared__ __align__(16) unsigned short xs[2][2][128][40];
  float4v O[24];
#pragma unroll
  for (int t = 0; t < 24; ++t) O[t] = (float4v){0.f, 0.f, 0.f, 0.f};

  const int srow = tid >> 2, sc4 = tid & 3;
  uint4 rh, rl;
  auto load_slice = [&](int ks) {
    size_t a = ((size_t)b * ND + n0 + srow) * CD + ks * 32 + sc4 * 8;
    rh = *(const uint4*)(xTh + a);
    rl = *(const uint4*)(xTl + a);
  };
  auto write_slice = [&](int buf) {
    *(uint4*)&xs[buf][0][srow][sc4 * 8] = rh;
    *(uint4*)&xs[buf][1][srow][sc4 * 8] = rl;
  };
  load_slice(0); write_slice(0);
#pragma unroll 1
  for (int ks = 0; ks < 8; ++ks) {
    __syncthreads();
    if (ks < 7) load_slice(ks + 1);
    short8v bxh = *(const short8v*)&xs[ks & 1][0][w * 16 + lq][quad * 8];
    short8v bxl = *(const short8v*)&xs[ks & 1][1][w * 16 + lq][quad * 8];
#pragma unroll
    for (int t = 0; t < 24; ++t) {
      size_t a = (size_t)(t * 16 + lq) * CD + ks * 32 + quad * 8;
      short8v awh = *(const short8v*)(Wch + a);
      short8v awl = *(const short8v*)(Wcl + a);
      O[t] = mfma16(awh, bxh, O[t]);
      O[t] = mfma16(awl, bxh, O[t]);
      O[t] = mfma16(awh, bxl, O[t]);
    }
    if (ks < 7) write_slice((ks + 1) & 1);
  }
  const int n = n0 + w * 16 + lq;
#pragma unroll
  for (int t = 0; t < 24; ++t) {
    if (t < 4) {
      ushort4 hh;
      hh.x = f2bf(O[t][0]); hh.y = f2bf(O[t][1]);
      hh.z = f2bf(O[t][2]); hh.w = f2bf(O[t][3]);
      *(ushort4*)&qh[((size_t)b * ND + n) * DA + t * 16 + quad * 4] = hh;
    } else if (t < 8) {
      ushort4 hh, ll;
      hh.x = f2bf(O[t][0]); hh.y = f2bf(O[t][1]);
      hh.z = f2bf(O[t][2]); hh.w = f2bf(O[t][3]);
      ll.x = f2bf(O[t][0] - bf2f(hh.x)); ll.y = f2bf(O[t][1] - bf2f(hh.y));
      ll.z = f2bf(O[t][2] - bf2f(hh.z)); ll.w = f2bf(O[t][3] - bf2f(hh.w));
      size_t o = ((size_t)b * ND + n) * DA + (t - 4) * 16 + quad * 4;
      *(ushort4*)&kh[o] = hh;
      *(ushort4*)&kl[o] = ll;
    } else {
#pragma unroll
      for (int r = 0; r < 4; ++r) {
        int c = (t - 8) * 16 + quad * 4 + r;
        vT[((size_t)b * CD + c) * ND + n] = f2bf(O[t][r]);
      }
    }
  }
}

// ---------------------------------------------------------------------------
// k_colsum: partial column sums of exp(e), e = qh*kh + qh*kl (2-product).
// COUNTED-vmcnt barriers; q-tile DMA staged 2-ahead into triple buffer.
// grid 512 (n-split halves), block 128m x 2048n.
// ---------------------------------------------------------------------------
__global__ __launch_bounds__(512, 4) void k_colsum(
    const unsigned short* __restrict__ qh, const unsigned short* __restrict__ khp,
    const unsigned short* __restrict__ klp, float* __restrict__ Dp) {
  const int bid = blockIdx.x, b = bid & 7, half = (bid >> 3) & 1,
            m0 = (bid >> 4) * 128;
  const int nbase = half * 2048;
  const int tid = threadIdx.x, w = tid >> 6, lane = tid & 63, lq = lane & 15,
            quad = lane >> 4;
  const int mq = w & 3, nh = w >> 2;
  __shared__ __align__(16) unsigned short qbuf[3][4096];  // 64n x 64d swizzled
  __shared__ float Cb[128];
  short8v bkh[2][2], bkl[2][2];
#pragma unroll
  for (int sub = 0; sub < 2; ++sub)
#pragma unroll
    for (int k = 0; k < 2; ++k) {
      size_t a = ((size_t)b * ND + m0 + mq * 32 + sub * 16 + lq) * DA + k * 32 + quad * 8;
      bkh[sub][k] = *(const short8v*)(khp + a);
      bkl[sub][k] = *(const short8v*)(klp + a);
    }
  // async staging: 512 chunks/tile, 1 per thread; swizzle baked into source
  const int srow = w * 8 + (lane >> 3), sck = lane & 7;
  auto stageQ = [&](int it, int qn) {
    const unsigned short* src = qh + ((size_t)b * ND + nbase + it * 64 + srow) * DA +
                                ((sck ^ (srow & 7)) << 3);
    gld16(src, &qbuf[qn][0] + (size_t)w * 512);
  };
  stageQ(0, 0);
  stageQ(1, 1);
  // stage(0) retired for everyone; stage(1) still in flight
  asm volatile("s_waitcnt vmcnt(1)\n\ts_barrier" ::: "memory");
  float cs0 = 0.f, cs1 = 0.f;
  int rc = 0, sc = 2;
#pragma unroll 1
  for (int i = 0; i < 32; ++i) {
    if (i < 30) { stageQ(i + 2, sc); sc = (sc + 1 == 3) ? 0 : sc + 1; }
#pragma unroll
    for (int s = 0; s < 2; ++s) {
      short8v ah[2];
#pragma unroll
      for (int k = 0; k < 2; ++k)
        ah[k] = *(const short8v*)&qbuf[rc][sw(nh * 32 + s * 16 + lq, k * 4 + quad)];
#pragma unroll
      for (int sub = 0; sub < 2; ++sub) {
        float4v acc = {0.f, 0.f, 0.f, 0.f};
#pragma unroll
        for (int k = 0; k < 2; ++k) {
          acc = mfma16(ah[k], bkh[sub][k], acc);
          acc = mfma16(ah[k], bkl[sub][k], acc);
        }
        float e0 = __expf(acc[0]) + __expf(acc[1]) + __expf(acc[2]) + __expf(acc[3]);
        if (sub == 0) cs0 += e0; else cs1 += e0;
      }
    }
    rc = (rc + 1 == 3) ? 0 : rc + 1;
    // counted barrier: stage(i+1) (older) retired, stage(i+2) stays in flight
    if (i < 30)
      asm volatile("s_waitcnt vmcnt(1) lgkmcnt(0)\n\ts_barrier" ::: "memory");
    else
      asm volatile("s_waitcnt vmcnt(0) lgkmcnt(0)\n\ts_barrier" ::: "memory");
  }
  cs0 += __shfl_down(cs0, 16); cs0 += __shfl_down(cs0, 32);
  cs1 += __shfl_down(cs1, 16); cs1 += __shfl_down(cs1, 32);
  if (nh == 0 && lane < 16) {
    Cb[mq * 32 + lane] = cs0;
    Cb[mq * 32 + 16 + lane] = cs1;
  }
  __syncthreads();
  if (nh == 1 && lane < 16) {
    float t0 = Cb[mq * 32 + lane] + cs0;
    float t1 = Cb[mq * 32 + 16 + lane] + cs1;
    size_t o = (size_t)half * (BD * ND) + (size_t)b * ND + m0 + mq * 32 + lane;
    Dp[o] = t0;
    Dp[o + 16] = t1;
  }
}

// combine halves: Drec = 1/(Dp0+Dp1). grid 32 x 256.
__global__ void k_rcp(const float* __restrict__ Dp, float* __restrict__ Drec) {
  int i = blockIdx.x * 256 + threadIdx.x;
  float4 a = *(const float4*)&Dp[(size_t)i * 4];
  float4 c = *(const float4*)&Dp[(size_t)(BD * ND) + (size_t)i * 4];
  float4 r;
  r.x = 1.f / (a.x + c.x); r.y = 1.f / (a.y + c.y);
  r.z = 1.f / (a.z + c.z); r.w = 1.f / (a.w + c.w);
  *(float4*)&Drec[(size_t)i * 4] = r;
}

// ---------------------------------------------------------------------------
// k_attn v3: flash main loop, BQ=128, BM=64, grid 256 (1 blk/CU), now
// *** 1024 threads = 16 waves = 4 waves/SIMD *** (was 8 waves = 2/SIMD).
// R0-R2 post-mortems: every pipe <25% busy at 2 waves/SIMD regardless of
// scheduling; this doubles TLP with identical structure & numerics.
// Waves = 4 n-quarters (nq) x 4 c/m-quarters (cq):
//   e-phase: wave computes E[32n x 16m] (swapped mfma(K,Q): lane holds 4
//            consecutive m), P packed uint2 into swizzled Pb (bit-identical
//            layout to R1). kc shrinks to 4 frags; drc4 to one float4.
//   PV:      wave computes O[64c x 32n]: t<4 c-tiles, O[2][4] accumulators.
//   S-reduce: quad-butterfly then 4-way cq combine via Sb4[4][128].
// Counted-vmcnt: stage = 2 chunks/thread -> vmcnt(2) barriers (stage(i+1)
// consumed at body(i+2), crosses 2 barriers; triple-buffered vbuf).
// ---------------------------------------------------------------------------
__global__ __launch_bounds__(1024, 4) void k_attn(
    const unsigned short* __restrict__ qh, const unsigned short* __restrict__ khp,
    const unsigned short* __restrict__ klp, const unsigned short* __restrict__ vT,
    const float* __restrict__ Drec, unsigned short* xhy,
    const unsigned short* __restrict__ xTl) {
  const int bid = blockIdx.x, b = bid & 7, n0 = (bid >> 3) * 128;
  const int tid = threadIdx.x, w = tid >> 6, lane = tid & 63, lq = lane & 15,
            quad = lane >> 4;
  const int nq = w & 3, cq = w >> 2;  // cq in [0,4)
  __shared__ __align__(16) unsigned short vbuf[3][16384];  // 256c x 64m swizzled
  __shared__ __align__(16) unsigned short Pb[2][8192];     // 128n x 64m swizzled
  __shared__ float Sb4[4][128];

  // q A-frags (hi only), resident
  short8v aq[2][2];
#pragma unroll
  for (int s = 0; s < 2; ++s)
#pragma unroll
    for (int k = 0; k < 2; ++k)
      aq[s][k] = *(const short8v*)(qh + ((size_t)b * ND + n0 + nq * 32 + s * 16 + lq) * DA +
                                   k * 32 + quad * 8);
  float4v O[2][4];
#pragma unroll
  for (int s = 0; s < 2; ++s)
#pragma unroll
    for (int t = 0; t < 4; ++t) O[s][t] = (float4v){0.f, 0.f, 0.f, 0.f};
  float rs[2] = {0.f, 0.f};

  // async vT staging: 2048 chunks, 2/thread, swizzle baked into source
  auto stageV = [&](int mt, int vn) {
    unsigned short* base = &vbuf[vn][0];
#pragma unroll
    for (int j = 0; j < 2; ++j) {
      int cidx = tid + j * 1024;
      int row = cidx >> 3, ckpos = cidx & 7;
      const unsigned short* src =
          vT + ((size_t)b * CD + row) * ND + mt * 64 + ((ckpos ^ (row & 7)) << 3);
      gld16(src, base + (size_t)(w * 64 + j * 1024) * 8);
    }
  };
  short8v kc[4], kn[4];  // [k*2 + (h|l)]; wave's 16 K-rows = m quarter cq
  auto kload = [&](short8v* dst, int mt) {
#pragma unroll
    for (int k = 0; k < 2; ++k) {
      size_t a = ((size_t)b * ND + mt * 64 + cq * 16 + lq) * DA + k * 32 + quad * 8;
      dst[k * 2 + 0] = *(const short8v*)(khp + a);
      dst[k * 2 + 1] = *(const short8v*)(klp + a);
    }
  };
  auto doPV = [&](const unsigned short* Pc, const unsigned short* vc) {
    short8v ap[2][2];
#pragma unroll
    for (int s = 0; s < 2; ++s)
#pragma unroll
      for (int k = 0; k < 2; ++k)
        ap[s][k] = *(const short8v*)&Pc[sw(nq * 32 + s * 16 + lq, k * 4 + quad)];
#pragma unroll
    for (int t = 0; t < 4; ++t) {
      const int trow = (cq * 4 + t) * 16 + lq;
#pragma unroll
      for (int k = 0; k < 2; ++k) {
        short8v bv = *(const short8v*)&vc[sw(trow, k * 4 + quad)];
#pragma unroll
        for (int s = 0; s < 2; ++s) O[s][t] = mfma16(bv, ap[s][k], O[s][t]);
      }
    }
  };

  float4 drc4, drn4;
  stageV(0, 0);
  kload(kc, 0);
  drc4 = *(const float4*)&Drec[(size_t)b * ND + cq * 16 + quad * 4];

  int vs = 1, vp = 0;
#pragma unroll 1
  for (int i = 0; i < 64; ++i) {
    if (i > 0) {
      doPV(&Pb[(i - 1) & 1][0], &vbuf[vp][0]);
      vp = (vp + 1 == 3) ? 0 : vp + 1;
    }
    if (i < 63) {
      // prefetch K/Drec FIRST (older in vmcnt order than the stage chunks)
      kload(kn, i + 1);
      drn4 = *(const float4*)&Drec[(size_t)b * ND + (i + 1) * 64 + cq * 16 + quad * 4];
      stageV(i + 1, vs);
      vs = (vs + 1 == 3) ? 0 : vs + 1;
    }
    // ---- e(i): 2-product K.Q^T (transposed out) -> P packed b64 writes ----
    unsigned short* Pcur = &Pb[i & 1][0];
#pragma unroll
    for (int s = 0; s < 2; ++s) {
      float4v acc = {0.f, 0.f, 0.f, 0.f};
#pragma unroll
      for (int k = 0; k < 2; ++k) {
        acc = mfma16(kc[k * 2 + 0], aq[s][k], acc);
        acc = mfma16(kc[k * 2 + 1], aq[s][k], acc);
      }
      // lane holds E[m = cq*16+quad*4+r][n = nq*32+s*16+lq]
      float p0 = __expf(acc[0]) * drc4.x;
      float p1 = __expf(acc[1]) * drc4.y;
      float p2 = __expf(acc[2]) * drc4.z;
      float p3 = __expf(acc[3]) * drc4.w;
      rs[s] += (p0 + p1) + (p2 + p3);
      unsigned int w0 =
          (__float_as_uint(p0) >> 16) | (__float_as_uint(p1) & 0xffff0000u);
      unsigned int w1 =
          (__float_as_uint(p2) >> 16) | (__float_as_uint(p3) & 0xffff0000u);
      const int nl = nq * 32 + s * 16 + lq;
      const int c8 = cq * 2 + (quad >> 1);
      uint2 wv; wv.x = w0; wv.y = w1;
      *(uint2*)&Pcur[nl * 64 + ((c8 ^ (nl & 7)) << 3) + ((quad & 1) << 2)] = wv;
    }
    if (i < 63) {
#pragma unroll
      for (int t = 0; t < 4; ++t) kc[t] = kn[t];
      drc4 = drn4;
    }
    // counted barrier: keep THIS body's 2 stage chunks in flight (they are
    // consumed at body(i+2)); everything older is retired in order.
    if (i < 63)
      asm volatile("s_waitcnt vmcnt(2) lgkmcnt(0)\n\ts_barrier" ::: "memory");
    else
      asm volatile("s_waitcnt vmcnt(0) lgkmcnt(0)\n\ts_barrier" ::: "memory");
  }
  doPV(&Pb[1][0], &vbuf[vp][0]);  // PV(63); 63&1 == 1, 63%3 == 0

  // ---- S reduction: butterfly over quad, then 4-way cq combine in LDS ----
  rs[0] += __shfl_xor(rs[0], 16); rs[0] += __shfl_xor(rs[0], 32);
  rs[1] += __shfl_xor(rs[1], 16); rs[1] += __shfl_xor(rs[1], 32);
  if (lane < 16) {
    Sb4[cq][nq * 32 + lane] = rs[0];
    Sb4[cq][nq * 32 + 16 + lane] = rs[1];
  }
  __syncthreads();
  float rsc[2];
#pragma unroll
  for (int s = 0; s < 2; ++s) {
    const int nloc = nq * 32 + s * 16 + lq;
    rsc[s] = 1.0f / (1e-9f + Sb4[0][nloc] + Sb4[1][nloc] + Sb4[2][nloc] + Sb4[3][nloc]);
  }
  // ---- y = x - O/S, in place over xTh (lane: 4 consecutive c, fixed n) ----
#pragma unroll
  for (int t = 0; t < 4; ++t) {
    const int cb = (cq * 4 + t) * 16 + quad * 4;
#pragma unroll
    for (int s = 0; s < 2; ++s) {
      const int n = n0 + nq * 32 + s * 16 + lq;
      const size_t off = ((size_t)b * ND + n) * CD + cb;
      ushort4 h4 = *(const ushort4*)&xhy[off];
      ushort4 l4 = *(const ushort4*)&xTl[off];
      ushort4 o4;
      o4.x = f2bf(bf2f(h4.x) + bf2f(l4.x) - O[s][t][0] * rsc[s]);
      o4.y = f2bf(bf2f(h4.y) + bf2f(l4.y) - O[s][t][1] * rsc[s]);
      o4.z = f2bf(bf2f(h4.z) + bf2f(l4.z) - O[s][t][2] * rsc[s]);
      o4.w = f2bf(bf2f(h4.w) + bf2f(l4.w) - O[s][t][3] * rsc[s]);
      *(ushort4*)&xhy[off] = o4;
    }
  }
}

// ---------------------------------------------------------------------------
// k_final: h = Wp . y (bf16 MFMA); out = relu(BN(h)) + x.
// ---------------------------------------------------------------------------
__global__ __launch_bounds__(256) void k_final(const unsigned short* __restrict__ y,
                                               const unsigned short* __restrict__ Wpb,
                                               const float* __restrict__ x,
                                               const float* __restrict__ gamma,
                                               const float* __restrict__ beta,
                                               const float* __restrict__ mean,
                                               const float* __restrict__ var,
                                               float* __restrict__ out) {
  const int bid = blockIdx.x;
  const int b = bid & 7;
  const int rem = bid >> 3;
  const int n0 = (rem & 63) * 64;
  const int d0 = (rem >> 6) * 64;
  const int tid = threadIdx.x;
  const int wave = tid >> 6, lane = tid & 63, lq = lane & 15, quad = lane >> 4;
  const int dw = d0 + wave * 16;
  float4v O[4];
#pragma unroll
  for (int s = 0; s < 4; ++s) O[s] = (float4v){0.f, 0.f, 0.f, 0.f};
#pragma unroll
  for (int chh = 0; chh < 8; ++chh) {
    const size_t ab = (size_t)(dw + lq) * CD + chh * 32 + quad * 8;
    short8v a0 = *(const short8v*)(Wpb + ab);
#pragma unroll
    for (int s = 0; s < 4; ++s) {
      const size_t bb = ((size_t)b * ND + n0 + s * 16 + lq) * CD + chh * 32 + quad * 8;
      short8v bv = *(const short8v*)(y + bb);
      O[s] = mfma16(a0, bv, O[s]);
    }
  }
#pragma unroll
  for (int r = 0; r < 4; ++r) {
    const int d = dw + quad * 4 + r;
    const float inv  = gamma[d] / sqrtf(var[d] + 1e-5f);
    const float bias = beta[d] - mean[d] * inv;
#pragma unroll
    for (int s = 0; s < 4; ++s) {
      const int n = n0 + s * 16 + lq;
      const size_t oi = ((size_t)b * CD + d) * ND + n;
      out[oi] = fmaxf(O[s][r] * inv + bias, 0.f) + x[oi];
    }
  }
}

extern "C" void kernel_launch(void* const* d_in, const int* in_sizes, int n_in,
                              void* d_out, int out_size, void* d_ws, size_t ws_size,
                              hipStream_t stream) {
  const float* x     = (const float*)d_in[0];
  const float* Wq    = (const float*)d_in[1];
  const float* Wk    = (const float*)d_in[2];
  const float* Wv    = (const float*)d_in[3];
  const float* Wp    = (const float*)d_in[4];
  const float* gamma = (const float*)d_in[5];
  const float* beta  = (const float*)d_in[6];
  const float* mean  = (const float*)d_in[7];
  const float* var   = (const float*)d_in[8];
  float* out = (float*)d_out;

  char* wsp = (char*)d_ws;
  unsigned short* qhp = (unsigned short*)wsp; wsp += (size_t)BD * ND * DA * 2;
  unsigned short* khp = (unsigned short*)wsp; wsp += (size_t)BD * ND * DA * 2;
  unsigned short* klp = (unsigned short*)wsp; wsp += (size_t)BD * ND * DA * 2;
  unsigned short* vT  = (unsigned short*)wsp; wsp += (size_t)BD * CD * ND * 2;
  unsigned short* xTh = (unsigned short*)wsp; wsp += (size_t)BD * ND * CD * 2;  // aliased as y
  unsigned short* xTl = (unsigned short*)wsp; wsp += (size_t)BD * ND * CD * 2;
  unsigned short* Wch = (unsigned short*)wsp; wsp += (size_t)384 * 256 * 2;
  unsigned short* Wcl = (unsigned short*)wsp; wsp += (size_t)384 * 256 * 2;
  unsigned short* Wph = (unsigned short*)wsp; wsp += (size_t)256 * 256 * 2;
  unsigned short* Wpl = (unsigned short*)wsp; wsp += (size_t)256 * 256 * 2;
  float* Drec = (float*)wsp; wsp += (size_t)BD * ND * 4;
  float* Dp   = (float*)wsp; wsp += (size_t)2 * BD * ND * 4;
  unsigned short* y = xTh;  // xTh consumed+overwritten by k_attn epilogue

  dim3 blk(256), blk5(512), blkA(1024);
  k_prep<<<dim3(ND / 64, CD / 64, BD), blk, 0, stream>>>(x, xTh, xTl);
  k_prepW<<<dim3(160), blk, 0, stream>>>(Wq, Wk, Wv, Wp, Wch, Wcl, Wph, Wpl);
  k_proj<<<dim3(ND / 128, BD), blk5, 0, stream>>>(xTh, xTl, Wch, Wcl, qhp, khp,
                                                  klp, vT);
  k_colsum<<<dim3(512), blk5, 0, stream>>>(qhp, khp, klp, Dp);
  k_rcp<<<dim3(32), blk, 0, stream>>>(Dp, Drec);
  k_attn<<<dim3(256), blkA, 0, stream>>>(qhp, khp, klp, vT, Drec, y, xTl);
  k_final<<<dim3(2048), blk, 0, stream>>>(y, Wph, x, gamma, beta, mean, var, out);
}